// Round 2
// baseline (695.124 us; speedup 1.0000x reference)
//
#include <hip/hip_runtime.h>
#include <hip/hip_bf16.h>

#define N_NODES 8192
#define DIM 64
#define VIS 2048
#define KIN 32
#define VOC 256

typedef unsigned short u16;

__device__ __forceinline__ float bf2f(u16 u) {
    union { unsigned int i; float f; } c; c.i = ((unsigned int)u) << 16; return c.f;
}
// fp32 -> bf16 round-to-nearest-even
__device__ __forceinline__ u16 f2bf(float f) {
    union { float f; unsigned int i; } c; c.f = f;
    unsigned int r = c.i + 0x7fffu + ((c.i >> 16) & 1u);
    return (u16)(r >> 16);
}
__device__ __forceinline__ float bflo(unsigned int w) {
    union { unsigned int i; float f; } c; c.i = w << 16; return c.f;
}
__device__ __forceinline__ float bfhi(unsigned int w) {
    union { unsigned int i; float f; } c; c.i = w & 0xffff0000u; return c.f;
}

// ---------------- Kernel 1: gather + mean over K, partial global stats ----
__global__ __launch_bounds__(256) void k_gather(
    const float* __restrict__ x, const float* __restrict__ memes,
    const int* __restrict__ idx, float* __restrict__ graw,
    float* __restrict__ part)
{
    int tid  = threadIdx.x;
    int wid  = tid >> 6;
    int lane = tid & 63;
    int n = blockIdx.x * 4 + wid;           // one wave per node
    const int* irow = idx + n * KIN;

    float acc = 0.f;
#pragma unroll
    for (int k = 0; k < KIN; ++k) {
        int id = irow[k];                   // wave-uniform load
        const float* row = (id < VIS) ? (x + (size_t)id * DIM)
                                      : (memes + (size_t)(id - VIS) * DIM);
        acc += row[lane];                   // 256B contiguous per wave
    }
    float g = acc * (1.0f / KIN);
    graw[(size_t)n * DIM + lane] = g;

    float s = g, q = g * g;
#pragma unroll
    for (int m = 32; m >= 1; m >>= 1) {
        s += __shfl_xor(s, m, 64);
        q += __shfl_xor(q, m, 64);
    }
    __shared__ float sh[8];
    if (lane == 0) { sh[wid] = s; sh[wid + 4] = q; }
    __syncthreads();
    if (tid == 0) {
        part[blockIdx.x * 2 + 0] = sh[0] + sh[1] + sh[2] + sh[3];
        part[blockIdx.x * 2 + 1] = sh[4] + sh[5] + sh[6] + sh[7];
    }
}

// ---------------- Kernel 2: finish global mean / inv-std (ddof=1) ---------
__global__ __launch_bounds__(1024) void k_stats(
    const float* __restrict__ part, float* __restrict__ scal)
{
    int tid = threadIdx.x;
    float s = 0.f, q = 0.f;
    for (int i = tid; i < 2048; i += 1024) {
        s += part[2 * i];
        q += part[2 * i + 1];
    }
#pragma unroll
    for (int m = 32; m >= 1; m >>= 1) {
        s += __shfl_xor(s, m, 64);
        q += __shfl_xor(q, m, 64);
    }
    __shared__ float sh[32];
    int wid = tid >> 6, lane = tid & 63;
    if (lane == 0) { sh[wid] = s; sh[wid + 16] = q; }
    __syncthreads();
    if (tid == 0) {
        float S = 0.f, Q = 0.f;
#pragma unroll
        for (int i = 0; i < 16; ++i) { S += sh[i]; Q += sh[i + 16]; }
        const float M = (float)(N_NODES * DIM);
        float mean = S / M;
        float var  = (Q - S * S / M) / (M - 1.0f);
        scal[0] = mean;
        scal[1] = 1.0f / sqrtf(var);
    }
}

// ---------------- Kernel 3: per-node routing + remix ----------------------
// One block per node. Vocab slice (64KiB fp32) staged ONCE from HBM into
// LDS as bf16 (32KiB, [e][v]); both einsums run from LDS.
__global__ __launch_bounds__(256, 4) void k_remix(
    const float* __restrict__ vocab, const float* __restrict__ graw,
    const float* __restrict__ scal,
    const float* __restrict__ rclip, const float* __restrict__ rsharp,
    float* __restrict__ out)
{
    __shared__ __align__(16) u16 vs[DIM * VOC];   // 32 KiB, [e][v] bf16
    __shared__ float g_s[DIM];
    __shared__ float p_s[VOC];
    __shared__ float red_s[VOC];
    __shared__ float sh[8];

    const int tid = threadIdx.x;
    const int n = blockIdx.x;
    const int wid = tid >> 6, lane = tid & 63;

    // standardized g into LDS (overlaps with staging loads below)
    if (tid < DIM) {
        float mean = scal[0], istd = scal[1];
        g_s[tid] = (graw[(size_t)n * DIM + tid] - mean) * istd;
    }

    // stage vocab slice: 16 x float4 per thread, convert to bf16
    const float4* vb4 = (const float4*)(vocab + (size_t)n * (DIM * VOC));
    ushort4* vs4 = (ushort4*)vs;
#pragma unroll
    for (int i = 0; i < 16; ++i) {
        float4 w = vb4[i * 256 + tid];        // wave reads 1KiB contiguous
        ushort4 h;
        h.x = f2bf(w.x); h.y = f2bf(w.y); h.z = f2bf(w.z); h.w = f2bf(w.w);
        vs4[i * 256 + tid] = h;               // ds_write_b64, conflict-free
    }
    __syncthreads();

    // ---- Pass A: d[v] = sum_e g[e] * vocab[e][v], v = tid ----
    float d = 0.f;
#pragma unroll
    for (int c = 0; c < 4; ++c) {
        float gg[16];
        *(float4*)&gg[0]  = *(const float4*)&g_s[c * 16 + 0];
        *(float4*)&gg[4]  = *(const float4*)&g_s[c * 16 + 4];
        *(float4*)&gg[8]  = *(const float4*)&g_s[c * 16 + 8];
        *(float4*)&gg[12] = *(const float4*)&g_s[c * 16 + 12];
        const u16* col = vs + (c * 16) * VOC + tid;
#pragma unroll
        for (int j = 0; j < 16; ++j)
            d = fmaf(gg[j], bf2f(col[j * VOC]), d);   // 2-way LDS alias: free
    }

    // ---- stats of d over 256 lanes (sum, sumsq), ddof=1 ----
    float s = d, q = d * d;
#pragma unroll
    for (int m = 32; m >= 1; m >>= 1) {
        s += __shfl_xor(s, m, 64);
        q += __shfl_xor(q, m, 64);
    }
    if (lane == 0) { sh[wid] = s; sh[wid + 4] = q; }
    __syncthreads();
    float S = sh[0] + sh[1] + sh[2] + sh[3];
    float Q = sh[4] + sh[5] + sh[6] + sh[7];
    float mD  = S * (1.0f / VOC);
    float var = (Q - S * S * (1.0f / VOC)) * (1.0f / (VOC - 1));
    float sdD = sqrtf(fmaxf(var, 0.f));

    float clip = expf(rclip[0]);                       // soft_clip
    float l2s  = rsharp[0] * 1.44269504088896f;        // log2(sharpness)

    float dn = (d - mD) / (sdD + 0.001f);
    float tt = tanhf(dn / clip) * clip;
    float p  = exp2f(tt * l2s);                        // sharpness ** tt
    p_s[tid] = p;

    float ps = p;
#pragma unroll
    for (int m = 32; m >= 1; m >>= 1) ps += __shfl_xor(ps, m, 64);
    __syncthreads();                 // protect sh; publish p_s
    if (lane == 0) sh[wid] = ps;
    __syncthreads();
    float invden = 1.0f / (sh[0] + sh[1] + sh[2] + sh[3] + 0.001f);

    // ---- Pass B: out[e] = invden * sum_v vocab[e][v] * p[v] ----
    // 4 threads per e, ds_read_b128 with e&7 chunk swizzle (bank spread)
    const int e = tid >> 2, qd = tid & 3;
    const u16* row = vs + e * VOC + qd * 64;
    const float* pp = p_s + qd * 64;
    const int i0 = e & 7;
    float acc = 0.f;
#pragma unroll
    for (int k = 0; k < 8; ++k) {
        int i = (i0 + k) & 7;
        uint4 w = *(const uint4*)(row + i * 8);        // 8 bf16
        const float* pj = pp + i * 8;
        acc = fmaf(bflo(w.x), pj[0], acc);
        acc = fmaf(bfhi(w.x), pj[1], acc);
        acc = fmaf(bflo(w.y), pj[2], acc);
        acc = fmaf(bfhi(w.y), pj[3], acc);
        acc = fmaf(bflo(w.z), pj[4], acc);
        acc = fmaf(bfhi(w.z), pj[5], acc);
        acc = fmaf(bflo(w.w), pj[6], acc);
        acc = fmaf(bfhi(w.w), pj[7], acc);
    }
    red_s[tid] = acc;
    __syncthreads();
    if (tid < DIM) {
        const float4 r = *(const float4*)&red_s[tid * 4];
        out[(size_t)n * DIM + tid] = (r.x + r.y + r.z + r.w) * invden;
    }
}

extern "C" void kernel_launch(void* const* d_in, const int* in_sizes, int n_in,
                              void* d_out, int out_size, void* d_ws, size_t ws_size,
                              hipStream_t stream)
{
    const float* x      = (const float*)d_in[0];
    const float* memes  = (const float*)d_in[1];
    const int*   idx    = (const int*)d_in[2];
    const float* vocab  = (const float*)d_in[3];
    const float* rclip  = (const float*)d_in[4];
    const float* rsharp = (const float*)d_in[5];
    float* out = (float*)d_out;

    float* scal = (float*)d_ws;                    // 2 floats
    float* part = (float*)((char*)d_ws + 64);      // 2048*2 floats (16 KiB)
    float* graw = (float*)((char*)d_ws + 32768);   // 8192*64 floats (2 MiB)

    k_gather<<<N_NODES / 4, 256, 0, stream>>>(x, memes, idx, graw, part);
    k_stats<<<1, 1024, 0, stream>>>(part, scal);
    k_remix<<<N_NODES, 256, 0, stream>>>(vocab, graw, scal, rclip, rsharp, out);
}